// Round 1
// baseline (706.216 us; speedup 1.0000x reference)
//
#include <hip/hip_runtime.h>
#include <math.h>

typedef unsigned short u16;
typedef __attribute__((ext_vector_type(4))) float f32x4;
typedef __attribute__((ext_vector_type(8))) short bf16x8;
typedef __attribute__((ext_vector_type(4))) unsigned short u16x4;
typedef __attribute__((ext_vector_type(8))) unsigned short u16x8;

#define DEVI static __device__ __forceinline__

DEVI float b2f(u16 u){ union{float f; unsigned i;} v; v.i = ((unsigned)u)<<16; return v.f; }
DEVI u16 f2b(float f){ union{float f; unsigned i;} v; v.f=f;
  unsigned r = v.i + 0x7fffu + ((v.i>>16)&1u); return (u16)(r>>16); }

DEVI void gload_lds16(const void* g, void* l){
  __builtin_amdgcn_global_load_lds((const __attribute__((address_space(1))) void*)g,
                                   (__attribute__((address_space(3))) void*)l, 16, 0, 0);
}

// ---------------------------------------------------------------------------
// W (512x512 f32, row-major [k][c]) -> Wt bf16 [c][k]
__global__ void prepw_k(const float* __restrict__ W, u16* __restrict__ Wt){
  int id = blockIdx.x*256 + threadIdx.x;         // 0..262143
  int k = id>>9, c = id&511;
  Wt[c*512 + k] = f2b(W[id]);
}

// f32 [nrows][512] -> bf16 [nrows][512] (+ optional row norms of the bf16 values)
__global__ void cvt_k(const float* __restrict__ src, u16* __restrict__ dst,
                      float* __restrict__ norms, int nrows){
  int gw = (int)((blockIdx.x*blockDim.x + threadIdx.x)>>6);
  int lane = threadIdx.x & 63;
  if (gw >= nrows) return;
  const float* s = src + (size_t)gw*512;
  u16* d = dst + (size_t)gw*512;
  float acc = 0.f;
  #pragma unroll
  for (int q=0;q<2;q++){
    f32x4 v = *(const f32x4*)(s + q*256 + lane*4);
    u16x4 u;
    #pragma unroll
    for (int e=0;e<4;e++){
      u16 b = f2b(v[e]); u[e] = b;
      float fv = b2f(b); acc += fv*fv;
    }
    *(u16x4*)(d + q*256 + lane*4) = u;
  }
  #pragma unroll
  for (int off=1;off<64;off<<=1) acc += __shfl_xor(acc, off);
  if (norms != nullptr && lane==0) norms[gw] = acc;
}

// row norms of a bf16 [nrows][512] matrix
__global__ void normb_k(const u16* __restrict__ src, float* __restrict__ norms, int nrows){
  int gw = (int)((blockIdx.x*blockDim.x + threadIdx.x)>>6);
  int lane = threadIdx.x & 63;
  if (gw >= nrows) return;
  const u16* s = src + (size_t)gw*512;
  u16x8 v = *(const u16x8*)(s + lane*8);
  float acc = 0.f;
  #pragma unroll
  for (int e=0;e<8;e++){ float f = b2f(v[e]); acc += f*f; }
  #pragma unroll
  for (int off=1;off<64;off<<=1) acc += __shfl_xor(acc, off);
  if (lane==0) norms[gw] = acc;
}

// ---------------------------------------------------------------------------
// OUT[r][c] = act(sum_k X[r][k]*W[k][c] + bias[c]) ; X bf16 [R][512], Wt bf16 [c][k]
// 128x128 tile, BK=64, global_load_lds(16B) + XOR-swizzled LDS (rule #21)
template<int ACT>
__global__ __launch_bounds__(256) void gemm_k(const u16* __restrict__ X,
    const u16* __restrict__ Wt, const float* __restrict__ bias, u16* __restrict__ OUT){
  __shared__ __align__(16) u16 sA[128*64];
  __shared__ __align__(16) u16 sB[128*64];
  const int tid = threadIdx.x, wave = tid>>6, lane = tid&63;
  const int rblk = blockIdx.x>>2, cb = (blockIdx.x&3)<<7;
  const u16* Xb = X + (size_t)rblk*(128*512);
  const u16* Wb = Wt + (size_t)cb*512;
  const int lrow = lane&15, lg = lane>>4, wr = wave>>1, wc = wave&1;
  f32x4 acc[4][4] = {};
  for (int s=0;s<8;s++){
    const int k0 = s<<6;
    #pragma unroll
    for (int q=0;q<4;q++){
      const int i = (wave<<2)+q;
      const int row = (i<<3) + (lane>>3);
      const int cd = (lane&7) ^ (row&7);       // pre-swizzled source chunk
      gload_lds16(Xb + row*512 + k0 + (cd<<3), sA + i*512);
      gload_lds16(Wb + row*512 + k0 + (cd<<3), sB + i*512);
    }
    __syncthreads();                            // vmcnt(0) drain + barrier
    #pragma unroll
    for (int kh=0;kh<2;kh++){
      bf16x8 a_[4], b_[4];
      #pragma unroll
      for (int i=0;i<4;i++){
        const int ra = (wr<<6)+(i<<4)+lrow;
        a_[i] = *(const bf16x8*)(sA + ra*64 + ((((kh<<2)+lg)^(ra&7))<<3));
        const int rb = (wc<<6)+(i<<4)+lrow;
        b_[i] = *(const bf16x8*)(sB + rb*64 + ((((kh<<2)+lg)^(rb&7))<<3));
      }
      #pragma unroll
      for (int i=0;i<4;i++)
        #pragma unroll
        for (int j=0;j<4;j++)
          acc[i][j] = __builtin_amdgcn_mfma_f32_16x16x32_bf16(a_[i], b_[j], acc[i][j], 0,0,0);
    }
    __syncthreads();
  }
  #pragma unroll
  for (int j=0;j<4;j++){
    const int col = cb + (wc<<6) + (j<<4) + lrow;
    const float bv = bias[col];
    #pragma unroll
    for (int i=0;i<4;i++){
      const int row0 = (rblk<<7) + (wr<<6) + (i<<4) + (lg<<2);
      #pragma unroll
      for (int r=0;r<4;r++){
        float v = acc[i][j][r] + bv;
        if (ACT) v = fmaxf(v, 0.f);
        OUT[(size_t)(row0+r)*512 + col] = f2b(v);
      }
    }
  }
}

// OUT[b][k][m] = sqrt(max(na[k]+nb[m]-2*dot(Xa[b][k],Xb[b][m]), 1e-6)); one block per batch
__global__ __launch_bounds__(256) void pdist_k(const u16* __restrict__ Xa,
    const u16* __restrict__ Xb2, const float* __restrict__ na, const float* __restrict__ nb,
    float* __restrict__ OUT){
  __shared__ __align__(16) u16 sA[128*64];
  __shared__ __align__(16) u16 sB[128*64];
  const int tid = threadIdx.x, wave = tid>>6, lane = tid&63;
  const int b = blockIdx.x;
  const u16* Ab = Xa + (size_t)b*(128*512);
  const u16* Bb = Xb2 + (size_t)b*(128*512);
  const int lrow = lane&15, lg = lane>>4, wr = wave>>1, wc = wave&1;
  f32x4 acc[4][4] = {};
  for (int s=0;s<8;s++){
    const int k0 = s<<6;
    #pragma unroll
    for (int q=0;q<4;q++){
      const int i = (wave<<2)+q;
      const int row = (i<<3) + (lane>>3);
      const int cd = (lane&7) ^ (row&7);
      gload_lds16(Ab + row*512 + k0 + (cd<<3), sA + i*512);
      gload_lds16(Bb + row*512 + k0 + (cd<<3), sB + i*512);
    }
    __syncthreads();
    #pragma unroll
    for (int kh=0;kh<2;kh++){
      bf16x8 a_[4], b_[4];
      #pragma unroll
      for (int i=0;i<4;i++){
        const int ra = (wr<<6)+(i<<4)+lrow;
        a_[i] = *(const bf16x8*)(sA + ra*64 + ((((kh<<2)+lg)^(ra&7))<<3));
        const int rb = (wc<<6)+(i<<4)+lrow;
        b_[i] = *(const bf16x8*)(sB + rb*64 + ((((kh<<2)+lg)^(rb&7))<<3));
      }
      #pragma unroll
      for (int i=0;i<4;i++)
        #pragma unroll
        for (int j=0;j<4;j++)
          acc[i][j] = __builtin_amdgcn_mfma_f32_16x16x32_bf16(a_[i], b_[j], acc[i][j], 0,0,0);
    }
    __syncthreads();
  }
  #pragma unroll
  for (int j=0;j<4;j++){
    const int col = (wc<<6)+(j<<4)+lrow;
    const float nbv = nb[b*128+col];
    #pragma unroll
    for (int i=0;i<4;i++){
      const int row0 = (wr<<6)+(i<<4)+(lg<<2);
      #pragma unroll
      for (int r=0;r<4;r++){
        float n2 = na[b*128+row0+r] + nbv - 2.0f*acc[i][j][r];
        OUT[(size_t)b*16384 + (size_t)(row0+r)*128 + col] = sqrtf(fmaxf(n2, 1e-6f));
      }
    }
  }
}

// ---------------------------------------------------------------------------
// mu/nu logs + T init (T = mu outer nu). 256 blocks x 128 threads.
__global__ void prep_k(const float* __restrict__ mask_q, const float* __restrict__ mask_r,
                       float* __restrict__ lmu, float* __restrict__ lnu,
                       float* __restrict__ Tm){
  int b = blockIdx.x, t = threadIdx.x;
  __shared__ float red[4];
  __shared__ float smu[128];
  float mq = mask_q[b*128+t], mr = mask_r[b*128+t];
  float s1 = mq, s2 = mr;
  #pragma unroll
  for (int off=1;off<64;off<<=1){ s1 += __shfl_xor(s1,off); s2 += __shfl_xor(s2,off); }
  if ((t&63)==0){ red[t>>6] = s1; red[2+(t>>6)] = s2; }
  __syncthreads();
  float sumq = red[0]+red[1], sumr = red[2]+red[3];
  float muv = mq/(sumq+1e-8f), nuv = mr/(sumr+1e-8f);
  lmu[b*128+t] = __logf(fmaxf(muv,1e-8f));
  lnu[b*128+t] = __logf(fmaxf(nuv,1e-8f));
  smu[t] = muv;
  __syncthreads();
  float* Tb = Tm + (size_t)b*16384;
  for (int k=0;k<128;k++) Tb[k*128+t] = smu[k]*nuv;   // coalesced
}

// ---------------------------------------------------------------------------
// TSr = T @ Sr (f32), plus a = rowsum(T), t2 = bvec @ Sr^2. One block/batch.
__global__ __launch_bounds__(256) void tsr_k(const float* __restrict__ Tm,
    const float* __restrict__ Sr, float* __restrict__ TSr,
    float* __restrict__ av_out, float* __restrict__ t2_out){
  int b = blockIdx.x, tid = threadIdx.x;
  __shared__ __align__(16) float Ts[128][132];
  __shared__ __align__(16) float Ss[128][132];
  __shared__ float bv[128];
  const float* Tb = Tm + (size_t)b*16384;
  const float* Sb = Sr + (size_t)b*16384;
  { int r = tid>>1, h = tid&1;
    #pragma unroll
    for (int q=0;q<16;q++){
      int c = h*64 + q*4;
      *(f32x4*)&Ts[r][c] = *(const f32x4*)(Tb + r*128 + c);
      *(f32x4*)&Ss[r][c] = *(const f32x4*)(Sb + r*128 + c);
    } }
  __syncthreads();
  if (tid < 128){
    float s=0.f;
    for (int k=0;k<128;k++) s += Ts[k][tid];
    bv[tid] = s;
  } else {
    int r = tid-128; float s=0.f;
    for (int m=0;m<128;m++) s += Ts[r][m];
    av_out[b*128+r] = s;
  }
  __syncthreads();
  if (tid < 128){
    float s=0.f;
    for (int m=0;m<128;m++){ float x = Ss[m][tid]; s += bv[m]*x*x; }
    t2_out[b*128+tid] = s;
  }
  const int ty = tid>>4, tx = tid&15;
  f32x4 acc[8][2] = {};
  for (int k=0;k<128;k++){
    float a_[8];
    #pragma unroll
    for (int i=0;i<8;i++) a_[i] = Ts[ty+16*i][k];
    f32x4 b0 = *(const f32x4*)&Ss[k][4*tx];
    f32x4 b1 = *(const f32x4*)&Ss[k][4*tx+64];
    #pragma unroll
    for (int i=0;i<8;i++){ acc[i][0] += a_[i]*b0; acc[i][1] += a_[i]*b1; }
  }
  float* Ob = TSr + (size_t)b*16384;
  #pragma unroll
  for (int i=0;i<8;i++)
    #pragma unroll
    for (int j=0;j<2;j++)
      *(f32x4*)(Ob + (ty+16*i)*128 + 4*tx + 64*j) = acc[i][j];
}

// G = Sq @ TSr; Cf = 0.5*C + 0.5*(t1 + t2 - 2G) with t1 = Sq^2 @ a. One block/batch.
__global__ __launch_bounds__(256) void lgw_k(const float* __restrict__ Sq,
    const float* __restrict__ TSr, const float* __restrict__ av_in,
    const float* __restrict__ t2_in, const float* __restrict__ Cin,
    float* __restrict__ Cf){
  int b = blockIdx.x, tid = threadIdx.x;
  __shared__ __align__(16) float As[128][132];
  __shared__ __align__(16) float Bs[128][132];
  __shared__ float a_s[128];
  __shared__ float t1s[128];
  __shared__ __align__(16) float t2s[128];
  const float* Ab = Sq + (size_t)b*16384;
  const float* Bb = TSr + (size_t)b*16384;
  { int r = tid>>1, h = tid&1;
    #pragma unroll
    for (int q=0;q<16;q++){
      int c = h*64 + q*4;
      *(f32x4*)&As[r][c] = *(const f32x4*)(Ab + r*128 + c);
      *(f32x4*)&Bs[r][c] = *(const f32x4*)(Bb + r*128 + c);
    } }
  if (tid<128){ a_s[tid] = av_in[b*128+tid]; t2s[tid] = t2_in[b*128+tid]; }
  __syncthreads();
  if (tid<128){
    float s=0.f;
    for (int l=0;l<128;l++){ float x = As[l][tid]; s += x*x*a_s[l]; }  // Sq symmetric
    t1s[tid] = s;
  }
  const int ty = tid>>4, tx = tid&15;
  f32x4 acc[8][2] = {};
  for (int k=0;k<128;k++){
    float a_[8];
    #pragma unroll
    for (int i=0;i<8;i++) a_[i] = As[ty+16*i][k];
    f32x4 b0 = *(const f32x4*)&Bs[k][4*tx];
    f32x4 b1 = *(const f32x4*)&Bs[k][4*tx+64];
    #pragma unroll
    for (int i=0;i<8;i++){ acc[i][0] += a_[i]*b0; acc[i][1] += a_[i]*b1; }
  }
  __syncthreads();   // t1s ready
  const float* Cb = Cin + (size_t)b*16384;
  float* Ob = Cf + (size_t)b*16384;
  #pragma unroll
  for (int i=0;i<8;i++){
    const int r = ty+16*i;
    const float t1v = t1s[r];
    #pragma unroll
    for (int j=0;j<2;j++){
      const int c = 4*tx + 64*j;
      f32x4 cv = *(const f32x4*)(Cb + r*128 + c);
      f32x4 t2v = *(const f32x4*)&t2s[c];
      f32x4 res;
      #pragma unroll
      for (int e=0;e<4;e++)
        res[e] = 0.5f*cv[e] + 0.5f*(t1v + t2v[e] - 2.f*acc[i][j][e]);
      *(f32x4*)(Ob + r*128 + c) = res;
    }
  }
}

// Fused 10-iter log-domain Sinkhorn + T update + cost/sim. One block/batch.
__global__ __launch_bounds__(256) void sink_k(const float* __restrict__ Cf,
    const float* __restrict__ lmu, const float* __restrict__ lnu,
    float* __restrict__ Tm, float* __restrict__ cost_out, float* __restrict__ sim_out,
    const float* __restrict__ log_eps){
  int b = blockIdx.x, tid = threadIdx.x;
  __shared__ float lk[128][129];
  __shared__ float lu[128], lv[128], lmus[128], lnus[128], red[4];
  float eps = __expf(log_eps[0]);
  eps = fminf(fmaxf(eps, 0.01f), 0.5f);
  const float rho = 0.1f/(0.1f+eps);
  const float inve = 1.0f/eps;
  const float* Cb = Cf + (size_t)b*16384;
  { int r = tid>>1, h = tid&1;
    #pragma unroll
    for (int q=0;q<16;q++){
      int c = h*64 + q*4;
      f32x4 v = *(const f32x4*)(Cb + r*128 + c);
      lk[r][c  ] = -v[0]*inve; lk[r][c+1] = -v[1]*inve;
      lk[r][c+2] = -v[2]*inve; lk[r][c+3] = -v[3]*inve;
    } }
  if (tid<128){ lu[tid]=0.f; lv[tid]=0.f;
                lmus[tid]=lmu[b*128+tid]; lnus[tid]=lnu[b*128+tid]; }
  __syncthreads();
  const int r2 = tid>>1, h = tid&1;
  for (int it=0; it<10; it++){
    float mx = -1e30f;
    for (int mi=0;mi<64;mi++){ int m = h*64+mi; mx = fmaxf(mx, lk[r2][m]+lv[m]); }
    mx = fmaxf(mx, __shfl_xor(mx,1));
    float s = 0.f;
    for (int mi=0;mi<64;mi++){ int m = h*64+mi; s += __expf(lk[r2][m]+lv[m]-mx); }
    s += __shfl_xor(s,1);
    if (h==0) lu[r2] = rho*(lmus[r2] - (mx + __logf(s)));
    __syncthreads();
    mx = -1e30f;
    for (int ki=0;ki<64;ki++){ int k = h*64+ki; mx = fmaxf(mx, lk[k][r2]+lu[k]); }
    mx = fmaxf(mx, __shfl_xor(mx,1));
    s = 0.f;
    for (int ki=0;ki<64;ki++){ int k = h*64+ki; s += __expf(lk[k][r2]+lu[k]-mx); }
    s += __shfl_xor(s,1);
    if (h==0) lv[r2] = rho*(lnus[r2] - (mx + __logf(s)));
    __syncthreads();
  }
  float cpart = 0.f;
  float* Tb = Tm + (size_t)b*16384;
  const int m = tid&127, ro = tid>>7;
  for (int kk=0;kk<64;kk++){
    int r = kk*2 + ro;
    float lkv = lk[r][m];
    float tv = __expf(lu[r] + lkv + lv[m]);
    Tb[r*128+m] = tv;                       // coalesced
    cpart += tv * (-eps*lkv);               // T * C_fgw
  }
  #pragma unroll
  for (int off=1;off<64;off<<=1) cpart += __shfl_xor(cpart, off);
  if ((tid&63)==0) red[tid>>6] = cpart;
  __syncthreads();
  if (tid==0){
    float tot = red[0]+red[1]+red[2]+red[3];
    cost_out[b] = tot;
    sim_out[b]  = 1.0f/(1.0f + __expf(tot));
  }
}

// ---------------------------------------------------------------------------
extern "C" void kernel_launch(void* const* d_in, const int* in_sizes, int n_in,
                              void* d_out, int out_size, void* d_ws, size_t ws_size,
                              hipStream_t stream){
  const float* sq      = (const float*)d_in[0];
  const float* sr      = (const float*)d_in[1];
  const float* mask_q  = (const float*)d_in[2];
  const float* mask_r  = (const float*)d_in[3];
  const float* cq      = (const float*)d_in[4];
  const float* cr      = (const float*)d_in[5];
  const float* W1      = (const float*)d_in[6];
  const float* b1      = (const float*)d_in[7];
  const float* W2      = (const float*)d_in[8];
  const float* b2      = (const float*)d_in[9];
  const float* log_eps = (const float*)d_in[10];

  float* out  = (float*)d_out;
  float* sim  = out;                 // [256]
  float* Tm   = out + 256;           // [256][128][128]
  float* Cm   = Tm + 4194304;        // [256][128][128]
  float* cost = Cm + 4194304;        // [256]

  char* ws = (char*)d_ws;
  size_t off = 0;
  auto alloc = [&](size_t bytes)->void*{ void* p = ws + off; off += (bytes+255)&~(size_t)255; return p; };
  u16*   SQB = (u16*)  alloc(33554432);   // sq bf16, later Pq
  u16*   SRB = (u16*)  alloc(33554432);   // sr bf16, later Pr (contiguous with SQB)
  u16*   HQ  = (u16*)  alloc(33554432);   // hidden q, later cq bf16
  u16*   HR  = (u16*)  alloc(33554432);   // hidden r, later cr bf16 (contiguous with HQ)
  u16*   W1T = (u16*)  alloc(524288);
  u16*   W2T = (u16*)  alloc(524288);
  float* NP  = (float*)alloc(262144);     // norms of P rows (65536)
  float* NCQ = (float*)alloc(131072);
  float* NCR = (float*)alloc(131072);
  float* LMU = (float*)alloc(131072);
  float* LNU = (float*)alloc(131072);
  float* AV  = (float*)alloc(131072);     // a = rowsum(T)
  float* T2V = (float*)alloc(131072);     // t2
  float* SQM = (float*)alloc(16777216);   // Sq
  float* SRM = (float*)alloc(16777216);   // Sr
  float* CFM = (float*)alloc(16777216);   // C_fgw
  float* TSRM= (float*)alloc(16777216);   // T@Sr
  (void)ws_size; (void)in_sizes; (void)n_in; (void)out_size;

  u16* PQ  = SQB;          // gemm2 output overwrites sq-bf16 region
  u16* CQB = HQ;           // centroid bf16 reuses hidden region (after gemm2)
  u16* CRB = HR;

  prepw_k<<<1024,256,0,stream>>>(W1, W1T);
  prepw_k<<<1024,256,0,stream>>>(W2, W2T);
  cvt_k<<<8192,256,0,stream>>>(sq, SQB, nullptr, 32768);
  cvt_k<<<8192,256,0,stream>>>(sr, SRB, nullptr, 32768);
  gemm_k<1><<<2048,256,0,stream>>>(SQB, W1T, b1, HQ);   // H = relu(X@W1+b1), 65536 rows
  gemm_k<0><<<2048,256,0,stream>>>(HQ, W2T, b2, PQ);    // P = H@W2+b2
  normb_k<<<16384,256,0,stream>>>(PQ, NP, 65536);
  cvt_k<<<8192,256,0,stream>>>(cq, CQB, NCQ, 32768);
  cvt_k<<<8192,256,0,stream>>>(cr, CRB, NCR, 32768);
  pdist_k<<<256,256,0,stream>>>(PQ, PQ + (size_t)32768*512, NP, NP + 32768, Cm);
  pdist_k<<<256,256,0,stream>>>(CQB, CQB, NCQ, NCQ, SQM);
  pdist_k<<<256,256,0,stream>>>(CRB, CRB, NCR, NCR, SRM);
  prep_k<<<256,128,0,stream>>>(mask_q, mask_r, LMU, LNU, Tm);
  for (int o=0;o<5;o++){
    tsr_k<<<256,256,0,stream>>>(Tm, SRM, TSRM, AV, T2V);
    lgw_k<<<256,256,0,stream>>>(SQM, TSRM, AV, T2V, Cm, CFM);
    sink_k<<<256,256,0,stream>>>(CFM, LMU, LNU, Tm, cost, sim, log_eps);
  }
}